// Round 9
// baseline (343.707 us; speedup 1.0000x reference)
//
#include <hip/hip_runtime.h>
#include <hip/hip_bf16.h>

typedef unsigned short u16;
typedef unsigned int u32;
typedef __attribute__((ext_vector_type(8))) short bf16x8;
typedef __attribute__((ext_vector_type(4))) float f32x4;
typedef __attribute__((ext_vector_type(8))) u16 u16x8;
typedef __attribute__((ext_vector_type(4))) u16 u16x4;

#define NN 20000
#define NE 320000
#define HC 512     // heads*channels = 4*128

__device__ __forceinline__ float bf2f(u16 u){ return __uint_as_float(((u32)u)<<16); }
__device__ __forceinline__ u16 f2bf(float x){
  __hip_bfloat16 h = __float2bfloat16(x);
  return *reinterpret_cast<u16*>(&h);
}
__device__ __forceinline__ float escore(float x){
  float e = x > 0.f ? x : 0.2f*x;
  return __expf(fminf(e, 80.f));
}

typedef const __attribute__((address_space(1))) unsigned int* gas_t;
typedef __attribute__((address_space(3))) unsigned int* las_t;
__device__ __forceinline__ void gl16(const void* g, void* l){
  __builtin_amdgcn_global_load_lds((gas_t)g, (las_t)l, 16, 0, 0);
}

// ---------------- cast x f32 -> bf16 ----------------
__global__ __launch_bounds__(256) void cast_kernel(const float* __restrict__ in, u16* __restrict__ out, int total){
  int i = (blockIdx.x*256 + threadIdx.x)*4;
  if (i >= total) return;
  float4 v = *(const float4*)(in + i);
  u16x4 o = { f2bf(v.x), f2bf(v.y), f2bf(v.z), f2bf(v.w) };
  *(u16x4*)(out + i) = o;
}

// ---------------- transpose+cast W f32 [K,N] -> WT bf16 [N,K] ----------------
__global__ __launch_bounds__(256) void transpose_cast(const float* __restrict__ W, u16* __restrict__ WT,
                                                      int K, int N){
  __shared__ u16 t[32][33];
  int bx = blockIdx.x*32;   // along N
  int by = blockIdx.y*32;   // along K
  int tx = threadIdx.x & 31, ty = threadIdx.x >> 5;  // 32x8
  for (int r = ty; r < 32; r += 8) t[r][tx] = f2bf(W[(size_t)(by+r)*N + bx + tx]);
  __syncthreads();
  for (int r = ty; r < 32; r += 8) WT[(size_t)(bx+r)*K + by + tx] = t[tx][r];
}

// ---------------- edge dtype detect ----------------
__global__ void detect_kernel(const int* __restrict__ ei, int* __restrict__ flag){
  __shared__ int nz;
  if (threadIdx.x == 0) nz = 0;
  __syncthreads();
  int c = 0;
  for (int k = threadIdx.x; k < 4096; k += 256) if (ei[2*k + 1] != 0) c++;
  atomicAdd(&nz, c);
  __syncthreads();
  if (threadIdx.x == 0) *flag = (nz == 0) ? 1 : 0;   // 1 => data is int64
}

// ---------------- normalize edges + histogram (fused) ----------------
__global__ __launch_bounds__(256) void normalize_hist(const int* __restrict__ ei, const int* __restrict__ flag,
    int* __restrict__ src, int* __restrict__ dst, int* __restrict__ cnt, int E){
  int e = blockIdx.x*256 + threadIdx.x;
  if (e >= E) return;
  int s, d;
  if (*flag){ s = ei[2*e]; d = ei[2*(E + e)]; }
  else      { s = ei[e];   d = ei[E + e]; }
  src[e] = s; dst[e] = d;
  atomicAdd(&cnt[d], 1);
}

// ---------------- GEMM + fused attention-coefficient epilogue ----------------
__global__ __launch_bounds__(256) void gemm_fused(const u16* __restrict__ A, const u16* __restrict__ BT,
                                                  u16* __restrict__ C,
                                                  const float* __restrict__ attS, const float* __restrict__ attD,
                                                  float* __restrict__ a_s, float* __restrict__ a_d,
                                                  int M, int K, int NBM){
  __shared__ __align__(16) u16 Ads[128][64];
  __shared__ __align__(16) u16 Bds[128][64];
  __shared__ float sred[128][2];
  __shared__ float dred[128][2];
  const int bid = blockIdx.x;
  const int xcd = bid & 7;
  const int seq = bid >> 3;
  const int bn  = seq & 3;
  const int bm  = (seq >> 2)*8 + xcd;
  if (bm >= NBM) return;
  const int tid = threadIdx.x;
  const int lane = tid & 63, wid = tid >> 6;
  const int wr = (wid >> 1) << 6, wc = (wid & 1) << 6;
  f32x4 acc[4][4] = {};
  const int row0 = bm*128;
  const int wbase = tid & 192;   // wave-uniform
  for (int k0 = 0; k0 < K; k0 += 64){
    #pragma unroll
    for (int p = 0; p < 4; ++p){
      int idx = p*256 + tid;
      int r = idx >> 3, cg = idx & 7;     // 16B granule column
      int csg = cg ^ (r & 7);             // pre-swizzled source granule
      int gr = row0 + r; if (gr >= M) gr = M - 1;   // clamp (rows >= M discarded at store)
      gl16(A + (size_t)gr*K + k0 + csg*8, (u16*)Ads + (size_t)(p*256 + wbase)*8);
      gl16(BT + (size_t)(bn*128 + r)*K + k0 + csg*8, (u16*)Bds + (size_t)(p*256 + wbase)*8);
    }
    __syncthreads();
    #pragma unroll
    for (int kk = 0; kk < 64; kk += 32){
      const int lr = lane & 15;
      const int lk = kk + ((lane >> 4) << 3);
      bf16x8 a[4], b[4];
      #pragma unroll
      for (int i = 0; i < 4; ++i){
        int ar = wr + 16*i + lr;
        a[i] = *(const bf16x8*)&Ads[ar][lk ^ ((ar & 7) << 3)];
      }
      #pragma unroll
      for (int j = 0; j < 4; ++j){
        int br = wc + 16*j + lr;
        b[j] = *(const bf16x8*)&Bds[br][lk ^ ((br & 7) << 3)];
      }
      #pragma unroll
      for (int i = 0; i < 4; ++i)
        #pragma unroll
        for (int j = 0; j < 4; ++j)
          acc[i][j] = __builtin_amdgcn_mfma_f32_16x16x32_bf16(a[i], b[j], acc[i][j], 0, 0, 0);
    }
    __syncthreads();
  }
  const int lr = lane & 15, r4 = (lane >> 4) << 2;
  #pragma unroll
  for (int i = 0; i < 4; ++i)
    #pragma unroll
    for (int j = 0; j < 4; ++j){
      int col = bn*128 + wc + 16*j + lr;
      #pragma unroll
      for (int r = 0; r < 4; ++r){
        int row = row0 + wr + 16*i + r4 + r;
        if (row < M) C[(size_t)row*HC + col] = f2bf(acc[i][j][r]);
      }
    }
  // ---- fused a_s/a_d epilogue ----
  float sv[4], dv[4];
  #pragma unroll
  for (int j = 0; j < 4; ++j){
    int cc = wc + 16*j + lr;            // 0..127 within head bn
    sv[j] = attS[bn*128 + cc];
    dv[j] = attD[bn*128 + cc];
  }
  #pragma unroll
  for (int i = 0; i < 4; ++i){
    #pragma unroll
    for (int r = 0; r < 4; ++r){
      float ps = acc[i][0][r]*sv[0] + acc[i][1][r]*sv[1] + acc[i][2][r]*sv[2] + acc[i][3][r]*sv[3];
      float pd = acc[i][0][r]*dv[0] + acc[i][1][r]*dv[1] + acc[i][2][r]*dv[2] + acc[i][3][r]*dv[3];
      #pragma unroll
      for (int off = 1; off < 16; off <<= 1){
        ps += __shfl_xor(ps, off, 64);
        pd += __shfl_xor(pd, off, 64);
      }
      if (lr == 0){
        int row = wr + 16*i + r4 + r;   // 0..127 (block-local)
        sred[row][wid & 1] = ps;
        dred[row][wid & 1] = pd;
      }
    }
  }
  __syncthreads();
  if (tid < 128){
    int row = row0 + tid;
    if (row < M){
      a_s[row*4 + bn] = sred[tid][0] + sred[tid][1];
      a_d[row*4 + bn] = dred[tid][0] + dred[tid][1];
    }
  }
}

// ---------------- scan (offsets) ----------------
__global__ __launch_bounds__(1024) void scan_kernel(const int* __restrict__ cnt,
    int* __restrict__ offs, int* __restrict__ cur, int N){
  __shared__ int bsum[1024];
  int tid = threadIdx.x;
  const int CH = (N + 1023) >> 10;
  int lo = tid*CH, hi = min(lo + CH, N);
  int s = 0;
  for (int i = lo; i < hi; ++i) s += cnt[i];
  bsum[tid] = s;
  __syncthreads();
  for (int off = 1; off < 1024; off <<= 1){
    int t = (tid >= off) ? bsum[tid - off] : 0;
    __syncthreads();
    bsum[tid] += t;
    __syncthreads();
  }
  int run = (tid > 0) ? bsum[tid - 1] : 0;
  for (int i = lo; i < hi; ++i){
    offs[i] = run; cur[i] = run; run += cnt[i];
  }
  if (tid == 1023) offs[N] = bsum[1023];
}

__global__ __launch_bounds__(256) void scatter_kernel(const int* __restrict__ src, const int* __restrict__ dst,
    int* __restrict__ cur, int* __restrict__ src_sorted, int E){
  int e = blockIdx.x*256 + threadIdx.x;
  if (e >= E) return;
  int d = dst[e];
  int pos = atomicAdd(&cur[d], 1);
  src_sorted[pos] = src[e];
}

// ---------------- alpha precompute: wave per dst, alpha = e/denom (sorted order) ----------------
__global__ __launch_bounds__(256) void alpha_kernel(const int* __restrict__ srcs, const int* __restrict__ offs,
    const float* __restrict__ a_s, const float* __restrict__ a_d,
    float* __restrict__ alpha, float* __restrict__ aself, int N){
  int d = blockIdx.x*4 + (threadIdx.x >> 6);
  if (d >= N) return;
  int lane = threadIdx.x & 63;
  int hh = lane & 3;
  float adv = a_d[d*4 + hh];
  float eself = escore(a_s[d*4 + hh] + adv);
  int p0 = offs[d], p1 = offs[d+1];
  float esum = 0.f;
  for (int base = p0; base < p1; base += 16){
    int el = base + (lane >> 2);
    if (el < p1){
      int s = srcs[el];
      esum += escore(a_s[s*4 + hh] + adv);
    }
  }
  esum += __shfl_xor(esum, 4, 64);
  esum += __shfl_xor(esum, 8, 64);
  esum += __shfl_xor(esum, 16, 64);
  esum += __shfl_xor(esum, 32, 64);
  float inv = 1.f/(esum + eself + 1e-16f);
  if (lane < 4) aself[d*4 + hh] = eself*inv;
  for (int base = p0; base < p1; base += 16){
    int el = base + (lane >> 2);
    if (el < p1){
      int s = srcs[el];
      alpha[(size_t)el*4 + hh] = escore(a_s[s*4 + hh] + adv)*inv;
    }
  }
}

// ---------------- 2-slice aggregation: slice parity pinned to XCD parity ----------------
// slice = bid&1 -> 256 channels (2 heads); per-XCD h working set = 10.2 MB half-table.
// 1 wave per (dst, slice); 8 B/lane (u16x4) -> 512 B/edge coalesced requests.
// alpha pre-normalized: no divide here.
// MODE 0: +bias, leaky(0.01) -> bf16 act.  MODE 2: 0.25*acc -> f32 head-mean partials.
template<int MODE>
__global__ __launch_bounds__(256) void agg2(const u16* __restrict__ h,
    const int* __restrict__ srcs, const int* __restrict__ offs,
    const float* __restrict__ alpha, const float* __restrict__ aself,
    const float* __restrict__ bias, void* __restrict__ outp, int N){
  const int bid = blockIdx.x;
  const int slice = bid & 1;                 // == XCD parity under round-robin dispatch
  const int d = (bid >> 1)*4 + (threadIdx.x >> 6);
  if (d >= N) return;
  const int lane = threadIdx.x & 63;
  const int ch = slice*256 + lane*4;         // 4 channels per lane
  const int head = ch >> 7;                  // 2*slice + (lane>>5)
  const u16* hb = h + ch;
  float a0, a1, a2, a3;
  {
    float w = aself[d*4 + head];
    u16x4 v = *(const u16x4*)(hb + (size_t)d*HC);
    a0 = w*bf2f(v[0]); a1 = w*bf2f(v[1]); a2 = w*bf2f(v[2]); a3 = w*bf2f(v[3]);
  }
  const int p0 = offs[d], p1 = offs[d+1];
  int p = p0;
  for (; p + 3 < p1; p += 4){
    int s0 = srcs[p], s1 = srcs[p+1], s2 = srcs[p+2], s3 = srcs[p+3];
    float w0 = alpha[(size_t)p*4 + head];
    float w1 = alpha[(size_t)(p+1)*4 + head];
    float w2 = alpha[(size_t)(p+2)*4 + head];
    float w3 = alpha[(size_t)(p+3)*4 + head];
    u16x4 v0 = *(const u16x4*)(hb + (size_t)s0*HC);
    u16x4 v1 = *(const u16x4*)(hb + (size_t)s1*HC);
    u16x4 v2 = *(const u16x4*)(hb + (size_t)s2*HC);
    u16x4 v3 = *(const u16x4*)(hb + (size_t)s3*HC);
    a0 += w0*bf2f(v0[0]) + w1*bf2f(v1[0]) + w2*bf2f(v2[0]) + w3*bf2f(v3[0]);
    a1 += w0*bf2f(v0[1]) + w1*bf2f(v1[1]) + w2*bf2f(v2[1]) + w3*bf2f(v3[1]);
    a2 += w0*bf2f(v0[2]) + w1*bf2f(v1[2]) + w2*bf2f(v2[2]) + w3*bf2f(v3[2]);
    a3 += w0*bf2f(v0[3]) + w1*bf2f(v1[3]) + w2*bf2f(v2[3]) + w3*bf2f(v3[3]);
  }
  for (; p < p1; ++p){
    int s = srcs[p];
    float w = alpha[(size_t)p*4 + head];
    u16x4 v = *(const u16x4*)(hb + (size_t)s*HC);
    a0 += w*bf2f(v[0]); a1 += w*bf2f(v[1]); a2 += w*bf2f(v[2]); a3 += w*bf2f(v[3]);
  }
  if (MODE == 0){
    float4 bb = *(const float4*)(bias + ch);
    float x0 = a0 + bb.x; x0 = x0 > 0.f ? x0 : 0.01f*x0;
    float x1 = a1 + bb.y; x1 = x1 > 0.f ? x1 : 0.01f*x1;
    float x2 = a2 + bb.z; x2 = x2 > 0.f ? x2 : 0.01f*x2;
    float x3 = a3 + bb.w; x3 = x3 > 0.f ? x3 : 0.01f*x3;
    u16x4 o = { f2bf(x0), f2bf(x1), f2bf(x2), f2bf(x3) };
    *(u16x4*)((u16*)outp + (size_t)d*HC + ch) = o;
  } else {
    f32x4 o = { 0.25f*a0, 0.25f*a1, 0.25f*a2, 0.25f*a3 };
    *(f32x4*)((float*)outp + (size_t)d*HC + ch) = o;
  }
}

// ---------------- fold head-mean partials + b3 -> split bf16 Hhi/Hlo ----------------
__global__ __launch_bounds__(256) void hsplit2_kernel(const float* __restrict__ part, const float* __restrict__ b3,
    u16* __restrict__ Hhi, u16* __restrict__ Hlo, int N){
  int idx = blockIdx.x*256 + threadIdx.x;   // N*32 items, 4 ch each
  if (idx >= N*32) return;
  int d = idx >> 5, c4 = (idx & 31)*4;
  const float* pp = part + (size_t)d*HC + c4;
  float4 q0 = *(const float4*)(pp);
  float4 q1 = *(const float4*)(pp + 128);
  float4 q2 = *(const float4*)(pp + 256);
  float4 q3 = *(const float4*)(pp + 384);
  float4 bb = *(const float4*)(b3 + c4);
  float r[4] = { q0.x+q1.x+q2.x+q3.x+bb.x, q0.y+q1.y+q2.y+q3.y+bb.y,
                 q0.z+q1.z+q2.z+q3.z+bb.z, q0.w+q1.w+q2.w+q3.w+bb.w };
  u16x4 hi, lo;
  #pragma unroll
  for (int t = 0; t < 4; ++t){
    hi[t] = f2bf(r[t]);
    lo[t] = f2bf(r[t] - bf2f(hi[t]));
  }
  *(u16x4*)(Hhi + (size_t)d*128 + c4) = hi;
  *(u16x4*)(Hlo + (size_t)d*128 + c4) = lo;
}

// ---------------- fc prep: transpose+split fcW f32 [128k x 128o] -> WThi/WTlo [o][k] ----------------
__global__ __launch_bounds__(256) void wsplit_kernel(const float* __restrict__ W,
    u16* __restrict__ WThi, u16* __restrict__ WTlo){
  int i = blockIdx.x*256 + threadIdx.x;   // 64 blocks * 256 = 16384
  int k = i >> 7, o = i & 127;
  float w = W[i];
  u16 hi = f2bf(w);
  u16 lo = f2bf(w - bf2f(hi));
  WThi[o*128 + k] = hi;
  WTlo[o*128 + k] = lo;
}

// ---------------- fc MFMA GEMM: z[M,128] = H[M,128] * WT[128,128]^T, split-precision ----------------
__global__ __launch_bounds__(256) void fc_mfma(const u16* __restrict__ Hhi, const u16* __restrict__ Hlo,
    const u16* __restrict__ WThi, const u16* __restrict__ WTlo,
    const float* __restrict__ fcb, float* __restrict__ outp, int M){
  __shared__ __align__(16) u16 Ahi[128][64];
  __shared__ __align__(16) u16 Alo[128][64];
  __shared__ __align__(16) u16 Bhi[128][64];
  __shared__ __align__(16) u16 Blo[128][64];
  const int tid = threadIdx.x;
  const int lane = tid & 63, wid = tid >> 6;
  const int wr = (wid >> 1) << 6, wc = (wid & 1) << 6;
  f32x4 acc[4][4] = {};
  const int row0 = blockIdx.x*128;
  for (int k0 = 0; k0 < 128; k0 += 64){
    #pragma unroll
    for (int p = 0; p < 4; ++p){
      int idx = p*256 + tid;
      int r = idx >> 3;
      int c = (idx & 7) << 3;
      int cs = c ^ ((r & 7) << 3);
      int gr = row0 + r; if (gr >= M) gr = M - 1;
      *(u16x8*)&Ahi[r][cs] = *(const u16x8*)(Hhi + (size_t)gr*128 + k0 + c);
      *(u16x8*)&Alo[r][cs] = *(const u16x8*)(Hlo + (size_t)gr*128 + k0 + c);
      *(u16x8*)&Bhi[r][cs] = *(const u16x8*)(WThi + (size_t)r*128 + k0 + c);
      *(u16x8*)&Blo[r][cs] = *(const u16x8*)(WTlo + (size_t)r*128 + k0 + c);
    }
    __syncthreads();
    #pragma unroll
    for (int kk = 0; kk < 64; kk += 32){
      const int lr = lane & 15;
      const int lk = kk + ((lane >> 4) << 3);
      bf16x8 ah[4], al[4], bh[4], bl[4];
      #pragma unroll
      for (int i = 0; i < 4; ++i){
        int ar = wr + 16*i + lr;
        int sw = lk ^ ((ar & 7) << 3);
        ah[i] = *(const bf16x8*)&Ahi[ar][sw];
        al[i] = *(const bf16x8*)&Alo[ar][sw];
      }
      #pragma unroll
      for (int j = 0; j < 4; ++j){
        int br = wc + 16*j + lr;
        int sw = lk ^ ((br & 7) << 3);
        bh[j] = *(const bf16x8*)&Bhi[br][sw];
        bl[j] = *(const bf16x8*)&Blo[br][sw];
      }
      #pragma unroll
      for (int i = 0; i < 4; ++i)
        #pragma unroll
        for (int j = 0; j < 4; ++j){
          acc[i][j] = __builtin_amdgcn_mfma_f32_16x16x32_bf16(ah[i], bh[j], acc[i][j], 0, 0, 0);
          acc[i][j] = __builtin_amdgcn_mfma_f32_16x16x32_bf16(ah[i], bl[j], acc[i][j], 0, 0, 0);
          acc[i][j] = __builtin_amdgcn_mfma_f32_16x16x32_bf16(al[i], bh[j], acc[i][j], 0, 0, 0);
        }
    }
    __syncthreads();
  }
  const int lr = lane & 15, r4 = (lane >> 4) << 2;
  #pragma unroll
  for (int i = 0; i < 4; ++i)
    #pragma unroll
    for (int j = 0; j < 4; ++j){
      int o = wc + 16*j + lr;
      float bb = fcb[o];
      #pragma unroll
      for (int r = 0; r < 4; ++r){
        int row = row0 + wr + 16*i + r4 + r;
        if (row < M){
          float z = acc[i][j][r] + bb;
          if (o < 64) outp[(size_t)row*64 + o] = z;
          else        outp[(size_t)M*64 + (size_t)row*64 + (o - 64)] = expf(z);
        }
      }
    }
}

extern "C" void kernel_launch(void* const* d_in, const int* in_sizes, int n_in,
                              void* d_out, int out_size, void* d_ws, size_t ws_size,
                              hipStream_t stream){
  const float* x    = (const float*)d_in[0];
  const int* ei     = (const int*)d_in[1];
  const float* W1   = (const float*)d_in[2];
  const float* att1s= (const float*)d_in[3];
  const float* att1d= (const float*)d_in[4];
  const float* b1   = (const float*)d_in[5];
  const float* W2   = (const float*)d_in[6];
  const float* att2s= (const float*)d_in[7];
  const float* att2d= (const float*)d_in[8];
  const float* b2   = (const float*)d_in[9];
  const float* W3   = (const float*)d_in[10];
  const float* att3s= (const float*)d_in[11];
  const float* att3d= (const float*)d_in[12];
  const float* b3   = (const float*)d_in[13];
  const float* fcW  = (const float*)d_in[14];
  const float* fcb  = (const float*)d_in[15];
  float* outp = (float*)d_out;

  char* ws = (char*)d_ws;
  size_t off = 0;
  auto alloc = [&](size_t bytes) -> void* {
    void* p = ws + off;
    off = (off + bytes + 255) & ~(size_t)255;
    return p;
  };
  u16*   xb     = (u16*)  alloc((size_t)NN*256*2);     // 10.2 MB
  u16*   h      = (u16*)  alloc((size_t)NN*HC*2);      // 20.5 MB
  u16*   act    = (u16*)  alloc((size_t)NN*HC*2);      // 20.5 MB
  float* hpart  = (float*)alloc((size_t)NN*HC*4);      // 41.0 MB (layer-3 f32 head partials)
  u16*   Hhi    = (u16*)  alloc((size_t)NN*128*2);     // 5.1 MB
  u16*   Hlo    = (u16*)  alloc((size_t)NN*128*2);     // 5.1 MB
  float* a_s    = (float*)alloc((size_t)NN*4*4);
  float* a_d    = (float*)alloc((size_t)NN*4*4);
  float* aself  = (float*)alloc((size_t)NN*4*4);
  float* alpha  = (float*)alloc((size_t)NE*4*4);       // 5.1 MB
  int*   cnt    = (int*)  alloc((size_t)NN*4);
  int*   cur    = (int*)  alloc((size_t)NN*4);
  int*   offs   = (int*)  alloc((size_t)(NN+1)*4);
  int*   src32  = (int*)  alloc((size_t)NE*4);
  int*   dst32  = (int*)  alloc((size_t)NE*4);
  int*   srcs   = (int*)  alloc((size_t)NE*4);
  u16*   WT1    = (u16*)  alloc((size_t)512*256*2);
  u16*   WT2    = (u16*)  alloc((size_t)512*512*2);
  u16*   WT3    = (u16*)  alloc((size_t)512*512*2);
  u16*   WThi   = (u16*)  alloc((size_t)128*128*2);
  u16*   WTlo   = (u16*)  alloc((size_t)128*128*2);
  int*   flag   = (int*)  alloc(256);

  // ---- input prep ----
  cast_kernel<<<5000, 256, 0, stream>>>(x, xb, NN*256);
  transpose_cast<<<dim3(16, 8),  256, 0, stream>>>(W1, WT1, 256, 512);
  transpose_cast<<<dim3(16, 16), 256, 0, stream>>>(W2, WT2, 512, 512);
  transpose_cast<<<dim3(16, 16), 256, 0, stream>>>(W3, WT3, 512, 512);
  wsplit_kernel<<<64, 256, 0, stream>>>(fcW, WThi, WTlo);

  detect_kernel<<<1, 256, 0, stream>>>(ei, flag);
  hipMemsetAsync(cnt, 0, (size_t)NN*4, stream);
  normalize_hist<<<1250, 256, 0, stream>>>(ei, flag, src32, dst32, cnt, NE);
  scan_kernel<<<1, 1024, 0, stream>>>(cnt, offs, cur, NN);
  scatter_kernel<<<1250, 256, 0, stream>>>(src32, dst32, cur, srcs, NE);

  const float* attS[3] = {att1s, att2s, att3s};
  const float* attD[3] = {att1d, att2d, att3d};
  const u16*   WT[3]   = {WT1, WT2, WT3};
  const int    Kd[3]   = {256, 512, 512};
  const int    NBM = 157;                 // ceil(20000/128)
  const int    gemm_grid = 8*((NBM + 7)/8)*4;
  const int    agg_grid = 2*((NN + 3)/4);   // 2 slices x 5000 groups

  for (int layer = 0; layer < 3; ++layer){
    const u16* Ain = (layer == 0) ? xb : act;
    gemm_fused<<<gemm_grid, 256, 0, stream>>>(Ain, WT[layer], h,
                                              attS[layer], attD[layer], a_s, a_d, NN, Kd[layer], NBM);
    alpha_kernel<<<5000, 256, 0, stream>>>(srcs, offs, a_s, a_d, alpha, aself, NN);
    if (layer == 0)
      agg2<0><<<agg_grid, 256, 0, stream>>>(h, srcs, offs, alpha, aself, b1, act, NN);
    else if (layer == 1)
      agg2<0><<<agg_grid, 256, 0, stream>>>(h, srcs, offs, alpha, aself, b2, act, NN);
    else
      agg2<2><<<agg_grid, 256, 0, stream>>>(h, srcs, offs, alpha, aself, b3, hpart, NN);
  }

  hsplit2_kernel<<<2500, 256, 0, stream>>>(hpart, b3, Hhi, Hlo, NN);
  fc_mfma<<<157, 256, 0, stream>>>(Hhi, Hlo, WThi, WTlo, fcb, outp, NN);
}

// Round 10
// 310.052 us; speedup vs baseline: 1.1085x; 1.1085x over previous
//
#include <hip/hip_runtime.h>
#include <hip/hip_bf16.h>

typedef unsigned short u16;
typedef unsigned int u32;
typedef __attribute__((ext_vector_type(8))) short bf16x8;
typedef __attribute__((ext_vector_type(4))) float f32x4;
typedef __attribute__((ext_vector_type(8))) u16 u16x8;
typedef __attribute__((ext_vector_type(4))) u16 u16x4;

#define NN 20000
#define NE 320000
#define HC 512     // heads*channels = 4*128

__device__ __forceinline__ float bf2f(u16 u){ return __uint_as_float(((u32)u)<<16); }
__device__ __forceinline__ u16 f2bf(float x){
  __hip_bfloat16 h = __float2bfloat16(x);
  return *reinterpret_cast<u16*>(&h);
}
__device__ __forceinline__ float escore(float x){
  float e = x > 0.f ? x : 0.2f*x;
  return __expf(fminf(e, 80.f));
}

typedef const __attribute__((address_space(1))) unsigned int* gas_t;
typedef __attribute__((address_space(3))) unsigned int* las_t;
__device__ __forceinline__ void gl16(const void* g, void* l){
  __builtin_amdgcn_global_load_lds((gas_t)g, (las_t)l, 16, 0, 0);
}

// ---------------- cast x f32 -> bf16 ----------------
__global__ __launch_bounds__(256) void cast_kernel(const float* __restrict__ in, u16* __restrict__ out, int total){
  int i = (blockIdx.x*256 + threadIdx.x)*4;
  if (i >= total) return;
  float4 v = *(const float4*)(in + i);
  u16x4 o = { f2bf(v.x), f2bf(v.y), f2bf(v.z), f2bf(v.w) };
  *(u16x4*)(out + i) = o;
}

// ---------------- transpose+cast W f32 [K,N] -> WT bf16 [N,K] ----------------
__global__ __launch_bounds__(256) void transpose_cast(const float* __restrict__ W, u16* __restrict__ WT,
                                                      int K, int N){
  __shared__ u16 t[32][33];
  int bx = blockIdx.x*32;   // along N
  int by = blockIdx.y*32;   // along K
  int tx = threadIdx.x & 31, ty = threadIdx.x >> 5;  // 32x8
  for (int r = ty; r < 32; r += 8) t[r][tx] = f2bf(W[(size_t)(by+r)*N + bx + tx]);
  __syncthreads();
  for (int r = ty; r < 32; r += 8) WT[(size_t)(bx+r)*K + by + tx] = t[tx][r];
}

// ---------------- edge dtype detect ----------------
__global__ void detect_kernel(const int* __restrict__ ei, int* __restrict__ flag){
  __shared__ int nz;
  if (threadIdx.x == 0) nz = 0;
  __syncthreads();
  int c = 0;
  for (int k = threadIdx.x; k < 4096; k += 256) if (ei[2*k + 1] != 0) c++;
  atomicAdd(&nz, c);
  __syncthreads();
  if (threadIdx.x == 0) *flag = (nz == 0) ? 1 : 0;   // 1 => data is int64
}

// ---------------- normalize edges + histogram (fused) ----------------
__global__ __launch_bounds__(256) void normalize_hist(const int* __restrict__ ei, const int* __restrict__ flag,
    int* __restrict__ src, int* __restrict__ dst, int* __restrict__ cnt, int E){
  int e = blockIdx.x*256 + threadIdx.x;
  if (e >= E) return;
  int s, d;
  if (*flag){ s = ei[2*e]; d = ei[2*(E + e)]; }
  else      { s = ei[e];   d = ei[E + e]; }
  src[e] = s; dst[e] = d;
  atomicAdd(&cnt[d], 1);
}

// ---------------- GEMM + fused attention-coefficient epilogue ----------------
__global__ __launch_bounds__(256) void gemm_fused(const u16* __restrict__ A, const u16* __restrict__ BT,
                                                  u16* __restrict__ C,
                                                  const float* __restrict__ attS, const float* __restrict__ attD,
                                                  float* __restrict__ a_s, float* __restrict__ a_d,
                                                  int M, int K, int NBM){
  __shared__ __align__(16) u16 Ads[128][64];
  __shared__ __align__(16) u16 Bds[128][64];
  __shared__ float sred[128][2];
  __shared__ float dred[128][2];
  const int bid = blockIdx.x;
  const int xcd = bid & 7;
  const int seq = bid >> 3;
  const int bn  = seq & 3;
  const int bm  = (seq >> 2)*8 + xcd;
  if (bm >= NBM) return;
  const int tid = threadIdx.x;
  const int lane = tid & 63, wid = tid >> 6;
  const int wr = (wid >> 1) << 6, wc = (wid & 1) << 6;
  f32x4 acc[4][4] = {};
  const int row0 = bm*128;
  const int wbase = tid & 192;   // wave-uniform
  for (int k0 = 0; k0 < K; k0 += 64){
    #pragma unroll
    for (int p = 0; p < 4; ++p){
      int idx = p*256 + tid;
      int r = idx >> 3, cg = idx & 7;     // 16B granule column
      int csg = cg ^ (r & 7);             // pre-swizzled source granule
      int gr = row0 + r; if (gr >= M) gr = M - 1;   // clamp (rows >= M discarded at store)
      gl16(A + (size_t)gr*K + k0 + csg*8, (u16*)Ads + (size_t)(p*256 + wbase)*8);
      gl16(BT + (size_t)(bn*128 + r)*K + k0 + csg*8, (u16*)Bds + (size_t)(p*256 + wbase)*8);
    }
    __syncthreads();
    #pragma unroll
    for (int kk = 0; kk < 64; kk += 32){
      const int lr = lane & 15;
      const int lk = kk + ((lane >> 4) << 3);
      bf16x8 a[4], b[4];
      #pragma unroll
      for (int i = 0; i < 4; ++i){
        int ar = wr + 16*i + lr;
        a[i] = *(const bf16x8*)&Ads[ar][lk ^ ((ar & 7) << 3)];
      }
      #pragma unroll
      for (int j = 0; j < 4; ++j){
        int br = wc + 16*j + lr;
        b[j] = *(const bf16x8*)&Bds[br][lk ^ ((br & 7) << 3)];
      }
      #pragma unroll
      for (int i = 0; i < 4; ++i)
        #pragma unroll
        for (int j = 0; j < 4; ++j)
          acc[i][j] = __builtin_amdgcn_mfma_f32_16x16x32_bf16(a[i], b[j], acc[i][j], 0, 0, 0);
    }
    __syncthreads();
  }
  const int lr = lane & 15, r4 = (lane >> 4) << 2;
  #pragma unroll
  for (int i = 0; i < 4; ++i)
    #pragma unroll
    for (int j = 0; j < 4; ++j){
      int col = bn*128 + wc + 16*j + lr;
      #pragma unroll
      for (int r = 0; r < 4; ++r){
        int row = row0 + wr + 16*i + r4 + r;
        if (row < M) C[(size_t)row*HC + col] = f2bf(acc[i][j][r]);
      }
    }
  // ---- fused a_s/a_d epilogue ----
  float sv[4], dv[4];
  #pragma unroll
  for (int j = 0; j < 4; ++j){
    int cc = wc + 16*j + lr;            // 0..127 within head bn
    sv[j] = attS[bn*128 + cc];
    dv[j] = attD[bn*128 + cc];
  }
  #pragma unroll
  for (int i = 0; i < 4; ++i){
    #pragma unroll
    for (int r = 0; r < 4; ++r){
      float ps = acc[i][0][r]*sv[0] + acc[i][1][r]*sv[1] + acc[i][2][r]*sv[2] + acc[i][3][r]*sv[3];
      float pd = acc[i][0][r]*dv[0] + acc[i][1][r]*dv[1] + acc[i][2][r]*dv[2] + acc[i][3][r]*dv[3];
      #pragma unroll
      for (int off = 1; off < 16; off <<= 1){
        ps += __shfl_xor(ps, off, 64);
        pd += __shfl_xor(pd, off, 64);
      }
      if (lr == 0){
        int row = wr + 16*i + r4 + r;   // 0..127 (block-local)
        sred[row][wid & 1] = ps;
        dred[row][wid & 1] = pd;
      }
    }
  }
  __syncthreads();
  if (tid < 128){
    int row = row0 + tid;
    if (row < M){
      a_s[row*4 + bn] = sred[tid][0] + sred[tid][1];
      a_d[row*4 + bn] = dred[tid][0] + dred[tid][1];
    }
  }
}

// ---------------- scan (offsets) ----------------
__global__ __launch_bounds__(1024) void scan_kernel(const int* __restrict__ cnt,
    int* __restrict__ offs, int* __restrict__ cur, int N){
  __shared__ int bsum[1024];
  int tid = threadIdx.x;
  const int CH = (N + 1023) >> 10;
  int lo = tid*CH, hi = min(lo + CH, N);
  int s = 0;
  for (int i = lo; i < hi; ++i) s += cnt[i];
  bsum[tid] = s;
  __syncthreads();
  for (int off = 1; off < 1024; off <<= 1){
    int t = (tid >= off) ? bsum[tid - off] : 0;
    __syncthreads();
    bsum[tid] += t;
    __syncthreads();
  }
  int run = (tid > 0) ? bsum[tid - 1] : 0;
  for (int i = lo; i < hi; ++i){
    offs[i] = run; cur[i] = run; run += cnt[i];
  }
  if (tid == 1023) offs[N] = bsum[1023];
}

__global__ __launch_bounds__(256) void scatter_kernel(const int* __restrict__ src, const int* __restrict__ dst,
    int* __restrict__ cur, int* __restrict__ src_sorted, int E){
  int e = blockIdx.x*256 + threadIdx.x;
  if (e >= E) return;
  int d = dst[e];
  int pos = atomicAdd(&cur[d], 1);
  src_sorted[pos] = src[e];
}

// ---------------- layers 1-2: 2-slice aggregation, inline escore, no alpha buffer ----------------
// slice = bid&1 (== XCD parity under round-robin) -> 256 channels (2 heads).
// 1 wave per (dst, slice); 8 B/lane gather; dsum computed redundantly per-lane (no shuffles).
__global__ __launch_bounds__(256) void agg2s(const u16* __restrict__ h,
    const int* __restrict__ srcs, const int* __restrict__ offs,
    const float* __restrict__ a_s, const float* __restrict__ a_d,
    const float* __restrict__ bias, u16* __restrict__ act, int N){
  const int bid = blockIdx.x;
  const int slice = bid & 1;
  const int d = (bid >> 1)*4 + (threadIdx.x >> 6);
  if (d >= N) return;
  const int lane = threadIdx.x & 63;
  const int ch = slice*256 + lane*4;         // 4 channels per lane
  const int head = ch >> 7;
  const u16* hb = h + ch;
  const float adv = a_d[d*4 + head];
  float a0, a1, a2, a3, dsum;
  {
    float w = escore(a_s[d*4 + head] + adv);   // self loop
    dsum = w;
    u16x4 v = *(const u16x4*)(hb + (size_t)d*HC);
    a0 = w*bf2f(v[0]); a1 = w*bf2f(v[1]); a2 = w*bf2f(v[2]); a3 = w*bf2f(v[3]);
  }
  const int p0 = offs[d], p1 = offs[d+1];
  int p = p0;
  for (; p + 3 < p1; p += 4){
    int s0 = srcs[p], s1 = srcs[p+1], s2 = srcs[p+2], s3 = srcs[p+3];
    float w0 = escore(a_s[s0*4 + head] + adv);
    float w1 = escore(a_s[s1*4 + head] + adv);
    float w2 = escore(a_s[s2*4 + head] + adv);
    float w3 = escore(a_s[s3*4 + head] + adv);
    u16x4 v0 = *(const u16x4*)(hb + (size_t)s0*HC);
    u16x4 v1 = *(const u16x4*)(hb + (size_t)s1*HC);
    u16x4 v2 = *(const u16x4*)(hb + (size_t)s2*HC);
    u16x4 v3 = *(const u16x4*)(hb + (size_t)s3*HC);
    dsum += w0 + w1 + w2 + w3;
    a0 += w0*bf2f(v0[0]) + w1*bf2f(v1[0]) + w2*bf2f(v2[0]) + w3*bf2f(v3[0]);
    a1 += w0*bf2f(v0[1]) + w1*bf2f(v1[1]) + w2*bf2f(v2[1]) + w3*bf2f(v3[1]);
    a2 += w0*bf2f(v0[2]) + w1*bf2f(v1[2]) + w2*bf2f(v2[2]) + w3*bf2f(v3[2]);
    a3 += w0*bf2f(v0[3]) + w1*bf2f(v1[3]) + w2*bf2f(v2[3]) + w3*bf2f(v3[3]);
  }
  for (; p < p1; ++p){
    int s = srcs[p];
    float w = escore(a_s[s*4 + head] + adv);
    u16x4 v = *(const u16x4*)(hb + (size_t)s*HC);
    dsum += w;
    a0 += w*bf2f(v[0]); a1 += w*bf2f(v[1]); a2 += w*bf2f(v[2]); a3 += w*bf2f(v[3]);
  }
  const float inv = 1.0f / (dsum + 1e-16f);
  float4 bb = *(const float4*)(bias + ch);
  float x0 = a0*inv + bb.x; x0 = x0 > 0.f ? x0 : 0.01f*x0;
  float x1 = a1*inv + bb.y; x1 = x1 > 0.f ? x1 : 0.01f*x1;
  float x2 = a2*inv + bb.z; x2 = x2 > 0.f ? x2 : 0.01f*x2;
  float x3 = a3*inv + bb.w; x3 = x3 > 0.f ? x3 : 0.01f*x3;
  u16x4 o = { f2bf(x0), f2bf(x1), f2bf(x2), f2bf(x3) };
  *(u16x4*)(act + (size_t)d*HC + ch) = o;
}

// ---------------- layer 3: full-width aggregation + head-mean + b3 + bf16 hi/lo split ----------------
__global__ __launch_bounds__(256) void aggf(const u16* __restrict__ h,
    const int* __restrict__ srcs, const int* __restrict__ offs,
    const float* __restrict__ a_s, const float* __restrict__ a_d,
    const float* __restrict__ b3, u16* __restrict__ Hhi, u16* __restrict__ Hlo, int N){
  int d = blockIdx.x*4 + (threadIdx.x >> 6);
  if (d >= N) return;
  int lane = threadIdx.x & 63;
  int head = lane >> 4;
  float adv = a_d[d*4 + head];
  float acc[8];
  float dsum;
  {
    float w = escore(a_s[d*4 + head] + adv);
    dsum = w;
    u16x8 v = *(const u16x8*)(h + (size_t)d*HC + lane*8);
    #pragma unroll
    for (int t = 0; t < 8; ++t) acc[t] = w*bf2f(v[t]);
  }
  int p0 = offs[d], p1 = offs[d+1];
  int p = p0;
  for (; p + 3 < p1; p += 4){
    int s0 = srcs[p], s1 = srcs[p+1], s2 = srcs[p+2], s3 = srcs[p+3];
    float w0 = escore(a_s[s0*4 + head] + adv);
    float w1 = escore(a_s[s1*4 + head] + adv);
    float w2 = escore(a_s[s2*4 + head] + adv);
    float w3 = escore(a_s[s3*4 + head] + adv);
    u16x8 v0 = *(const u16x8*)(h + (size_t)s0*HC + lane*8);
    u16x8 v1 = *(const u16x8*)(h + (size_t)s1*HC + lane*8);
    u16x8 v2 = *(const u16x8*)(h + (size_t)s2*HC + lane*8);
    u16x8 v3 = *(const u16x8*)(h + (size_t)s3*HC + lane*8);
    dsum += w0 + w1 + w2 + w3;
    #pragma unroll
    for (int t = 0; t < 8; ++t)
      acc[t] += w0*bf2f(v0[t]) + w1*bf2f(v1[t]) + w2*bf2f(v2[t]) + w3*bf2f(v3[t]);
  }
  for (; p < p1; ++p){
    int s = srcs[p];
    float w = escore(a_s[s*4 + head] + adv);
    u16x8 v = *(const u16x8*)(h + (size_t)s*HC + lane*8);
    dsum += w;
    #pragma unroll
    for (int t = 0; t < 8; ++t) acc[t] += w*bf2f(v[t]);
  }
  float inv = 1.0f / (dsum + 1e-16f);
  #pragma unroll
  for (int t = 0; t < 8; ++t){
    acc[t] *= inv;
    acc[t] += __shfl_xor(acc[t], 16, 64);
    acc[t] += __shfl_xor(acc[t], 32, 64);
  }
  if (lane < 16){
    int c0 = lane*8;
    u16x8 hi, lo;
    #pragma unroll
    for (int t = 0; t < 8; ++t){
      float r = 0.25f*acc[t] + b3[c0 + t];
      hi[t] = f2bf(r);
      lo[t] = f2bf(r - bf2f(hi[t]));
    }
    *(u16x8*)(Hhi + (size_t)d*128 + c0) = hi;
    *(u16x8*)(Hlo + (size_t)d*128 + c0) = lo;
  }
}

// ---------------- fc prep: transpose+split fcW f32 [128k x 128o] -> WThi/WTlo [o][k] ----------------
__global__ __launch_bounds__(256) void wsplit_kernel(const float* __restrict__ W,
    u16* __restrict__ WThi, u16* __restrict__ WTlo){
  int i = blockIdx.x*256 + threadIdx.x;   // 64 blocks * 256 = 16384
  int k = i >> 7, o = i & 127;
  float w = W[i];
  u16 hi = f2bf(w);
  u16 lo = f2bf(w - bf2f(hi));
  WThi[o*128 + k] = hi;
  WTlo[o*128 + k] = lo;
}

// ---------------- fc MFMA GEMM: z[M,128] = H[M,128] * WT[128,128]^T, split-precision ----------------
__global__ __launch_bounds__(256) void fc_mfma(const u16* __restrict__ Hhi, const u16* __restrict__ Hlo,
    const u16* __restrict__ WThi, const u16* __restrict__ WTlo,
    const float* __restrict__ fcb, float* __restrict__ outp, int M){
  __shared__ __align__(16) u16 Ahi[128][64];
  __shared__ __align__(16) u16 Alo[128][64];
  __shared__ __align__(16) u16 Bhi[128][64];
  __shared__ __align__(16) u16 Blo[128][64];
  const int tid = threadIdx.x;
  const int lane = tid & 63, wid = tid >> 6;
  const int wr = (wid >> 1) << 6, wc = (wid & 1) << 6;
  f32x4 acc[4][4] = {};
  const int row0 = blockIdx.x*128;
  for (int k0 = 0; k0 < 128; k0 += 64){
    #pragma unroll
    for (int p = 0; p < 4; ++p){
      int idx = p*256 + tid;
      int r = idx >> 3;
      int c = (idx & 7) << 3;
      int cs = c ^ ((r & 7) << 3);
      int gr = row0 + r; if (gr >= M) gr = M - 1;
      *(u16x8*)&Ahi[r][cs] = *(const u16x8*)(Hhi + (size_t)gr*128 + k0 + c);
      *(u16x8*)&Alo[r][cs] = *(const u16x8*)(Hlo + (size_t)gr*128 + k0 + c);
      *(u16x8*)&Bhi[r][cs] = *(const u16x8*)(WThi + (size_t)r*128 + k0 + c);
      *(u16x8*)&Blo[r][cs] = *(const u16x8*)(WTlo + (size_t)r*128 + k0 + c);
    }
    __syncthreads();
    #pragma unroll
    for (int kk = 0; kk < 64; kk += 32){
      const int lr = lane & 15;
      const int lk = kk + ((lane >> 4) << 3);
      bf16x8 ah[4], al[4], bh[4], bl[4];
      #pragma unroll
      for (int i = 0; i < 4; ++i){
        int ar = wr + 16*i + lr;
        int sw = lk ^ ((ar & 7) << 3);
        ah[i] = *(const bf16x8*)&Ahi[ar][sw];
        al[i] = *(const bf16x8*)&Alo[ar][sw];
      }
      #pragma unroll
      for (int j = 0; j < 4; ++j){
        int br = wc + 16*j + lr;
        int sw = lk ^ ((br & 7) << 3);
        bh[j] = *(const bf16x8*)&Bhi[br][sw];
        bl[j] = *(const bf16x8*)&Blo[br][sw];
      }
      #pragma unroll
      for (int i = 0; i < 4; ++i)
        #pragma unroll
        for (int j = 0; j < 4; ++j){
          acc[i][j] = __builtin_amdgcn_mfma_f32_16x16x32_bf16(ah[i], bh[j], acc[i][j], 0, 0, 0);
          acc[i][j] = __builtin_amdgcn_mfma_f32_16x16x32_bf16(ah[i], bl[j], acc[i][j], 0, 0, 0);
          acc[i][j] = __builtin_amdgcn_mfma_f32_16x16x32_bf16(al[i], bh[j], acc[i][j], 0, 0, 0);
        }
    }
    __syncthreads();
  }
  const int lr = lane & 15, r4 = (lane >> 4) << 2;
  #pragma unroll
  for (int i = 0; i < 4; ++i)
    #pragma unroll
    for (int j = 0; j < 4; ++j){
      int o = wc + 16*j + lr;
      float bb = fcb[o];
      #pragma unroll
      for (int r = 0; r < 4; ++r){
        int row = row0 + wr + 16*i + r4 + r;
        if (row < M){
          float z = acc[i][j][r] + bb;
          if (o < 64) outp[(size_t)row*64 + o] = z;
          else        outp[(size_t)M*64 + (size_t)row*64 + (o - 64)] = expf(z);
        }
      }
    }
}

extern "C" void kernel_launch(void* const* d_in, const int* in_sizes, int n_in,
                              void* d_out, int out_size, void* d_ws, size_t ws_size,
                              hipStream_t stream){
  const float* x    = (const float*)d_in[0];
  const int* ei     = (const int*)d_in[1];
  const float* W1   = (const float*)d_in[2];
  const float* att1s= (const float*)d_in[3];
  const float* att1d= (const float*)d_in[4];
  const float* b1   = (const float*)d_in[5];
  const float* W2   = (const float*)d_in[6];
  const float* att2s= (const float*)d_in[7];
  const float* att2d= (const float*)d_in[8];
  const float* b2   = (const float*)d_in[9];
  const float* W3   = (const float*)d_in[10];
  const float* att3s= (const float*)d_in[11];
  const float* att3d= (const float*)d_in[12];
  const float* b3   = (const float*)d_in[13];
  const float* fcW  = (const float*)d_in[14];
  const float* fcb  = (const float*)d_in[15];
  float* outp = (float*)d_out;

  char* ws = (char*)d_ws;
  size_t off = 0;
  auto alloc = [&](size_t bytes) -> void* {
    void* p = ws + off;
    off = (off + bytes + 255) & ~(size_t)255;
    return p;
  };
  u16*   xb     = (u16*)  alloc((size_t)NN*256*2);     // 10.2 MB
  u16*   h      = (u16*)  alloc((size_t)NN*HC*2);      // 20.5 MB
  u16*   act    = (u16*)  alloc((size_t)NN*HC*2);      // 20.5 MB
  u16*   Hhi    = (u16*)  alloc((size_t)NN*128*2);     // 5.1 MB
  u16*   Hlo    = (u16*)  alloc((size_t)NN*128*2);     // 5.1 MB
  float* a_s    = (float*)alloc((size_t)NN*4*4);
  float* a_d    = (float*)alloc((size_t)NN*4*4);
  int*   cnt    = (int*)  alloc((size_t)NN*4);
  int*   cur    = (int*)  alloc((size_t)NN*4);
  int*   offs   = (int*)  alloc((size_t)(NN+1)*4);
  int*   src32  = (int*)  alloc((size_t)NE*4);
  int*   dst32  = (int*)  alloc((size_t)NE*4);
  int*   srcs   = (int*)  alloc((size_t)NE*4);
  u16*   WT1    = (u16*)  alloc((size_t)512*256*2);
  u16*   WT2    = (u16*)  alloc((size_t)512*512*2);
  u16*   WT3    = (u16*)  alloc((size_t)512*512*2);
  u16*   WThi   = (u16*)  alloc((size_t)128*128*2);
  u16*   WTlo   = (u16*)  alloc((size_t)128*128*2);
  int*   flag   = (int*)  alloc(256);

  // ---- input prep ----
  cast_kernel<<<5000, 256, 0, stream>>>(x, xb, NN*256);
  transpose_cast<<<dim3(16, 8),  256, 0, stream>>>(W1, WT1, 256, 512);
  transpose_cast<<<dim3(16, 16), 256, 0, stream>>>(W2, WT2, 512, 512);
  transpose_cast<<<dim3(16, 16), 256, 0, stream>>>(W3, WT3, 512, 512);
  wsplit_kernel<<<64, 256, 0, stream>>>(fcW, WThi, WTlo);

  detect_kernel<<<1, 256, 0, stream>>>(ei, flag);
  hipMemsetAsync(cnt, 0, (size_t)NN*4, stream);
  normalize_hist<<<1250, 256, 0, stream>>>(ei, flag, src32, dst32, cnt, NE);
  scan_kernel<<<1, 1024, 0, stream>>>(cnt, offs, cur, NN);
  scatter_kernel<<<1250, 256, 0, stream>>>(src32, dst32, cur, srcs, NE);

  const float* attS[3] = {att1s, att2s, att3s};
  const float* attD[3] = {att1d, att2d, att3d};
  const u16*   WT[3]   = {WT1, WT2, WT3};
  const int    Kd[3]   = {256, 512, 512};
  const int    NBM = 157;                 // ceil(20000/128)
  const int    gemm_grid = 8*((NBM + 7)/8)*4;
  const int    agg_grid = 2*((NN + 3)/4);   // 2 slices x 5000 groups

  for (int layer = 0; layer < 3; ++layer){
    const u16* Ain = (layer == 0) ? xb : act;
    gemm_fused<<<gemm_grid, 256, 0, stream>>>(Ain, WT[layer], h,
                                              attS[layer], attD[layer], a_s, a_d, NN, Kd[layer], NBM);
    if (layer == 0)
      agg2s<<<agg_grid, 256, 0, stream>>>(h, srcs, offs, a_s, a_d, b1, act, NN);
    else if (layer == 1)
      agg2s<<<agg_grid, 256, 0, stream>>>(h, srcs, offs, a_s, a_d, b2, act, NN);
    else
      aggf<<<5000, 256, 0, stream>>>(h, srcs, offs, a_s, a_d, b3, Hhi, Hlo, NN);
  }

  fc_mfma<<<157, 256, 0, stream>>>(Hhi, Hlo, WThi, WTlo, fcb, outp, NN);
}